// Round 4
// baseline (472.931 us; speedup 1.0000x reference)
//
#include <hip/hip_runtime.h>
#include <stdint.h>

#define NN 50000
#define NE 500000
#define SPB 64                    // slots per k_edge2 block; C[64][128] f32 = 32 KB
#define HP_BLOCKS ((NN + 127) / 128)          // 391
#define DEG_STRIDE (HP_BLOCKS * 256)          // 100096

typedef short bf16x8 __attribute__((ext_vector_type(8)));
typedef float f32x4 __attribute__((ext_vector_type(4)));
typedef unsigned short u16;
typedef unsigned short u16x4 __attribute__((ext_vector_type(4)));
typedef unsigned int u32x4 __attribute__((ext_vector_type(4)));

__device__ __forceinline__ u16 f2b(float x) {
  uint32_t u = __builtin_bit_cast(uint32_t, x);
  return (u16)((u + 0x7fffu + ((u >> 16) & 1u)) >> 16);
}
__device__ __forceinline__ float b2f(uint32_t lo16) {
  return __builtin_bit_cast(float, lo16 << 16);
}

// JAX threefry2x32, key = jax.random.key(42) -> (0, 42)
__device__ __forceinline__ void threefry(uint32_t x0, uint32_t x1,
                                         uint32_t& o0, uint32_t& o1) {
  const uint32_t k0 = 0u, k1 = 42u, k2 = 0u ^ 42u ^ 0x1BD11BDAu;
  x0 += k0; x1 += k1;
#define TFR(r) { x0 += x1; x1 = (x1 << r) | (x1 >> (32 - r)); x1 ^= x0; }
  TFR(13) TFR(15) TFR(26) TFR(6)
  x0 += k1; x1 += k2 + 1u;
  TFR(17) TFR(29) TFR(16) TFR(24)
  x0 += k2; x1 += k0 + 2u;
  TFR(13) TFR(15) TFR(26) TFR(6)
  x0 += k0; x1 += k1 + 3u;
  TFR(17) TFR(29) TFR(16) TFR(24)
  x0 += k1; x1 += k2 + 4u;
  TFR(13) TFR(15) TFR(26) TFR(6)
  x0 += k2; x1 += k0 + 5u;
#undef TFR
  o0 = x0; o1 = x1;
}

// JAX partitionable random_bits: bits(j) = o0^o1 of threefry(0, j)
__device__ __forceinline__ bool jax_keep(uint32_t j) {
  uint32_t o0, o1;
  threefry(0u, j, o0, o1);
  uint32_t bits = o0 ^ o1;
  float u = __builtin_bit_cast(float, (bits >> 9) | 0x3f800000u) - 1.0f;
  return u < 0.9f;
}

// 128x128 tile, 4 waves each 64x64, K=128 (used by k_hp / k_out).
template <int K, int GM>
__device__ __forceinline__ void mfma_tile(const u16* sA, const u16* sBT,
                                          int t, f32x4 (&c)[4][4]) {
  const int lane = t & 63, w = t >> 6;
  const int wr = (w & 1) << 6, wc = (w >> 1) << 6;
  const int quad = lane >> 4, lr = lane & 15;
#pragma unroll
  for (int i = 0; i < 4; ++i)
#pragma unroll
    for (int j = 0; j < 4; ++j) { f32x4 z = {0.f, 0.f, 0.f, 0.f}; c[i][j] = z; }
#pragma unroll
  for (int ks = 0; ks < K; ks += 32) {
    const int kg = (ks >> 3) + quad;
    bf16x8 a[4], b[4];
#pragma unroll
    for (int i = 0; i < 4; ++i) {
      int row = wr + (i << 4) + lr;
      a[i] = *(const bf16x8*)&sA[row * K + ((kg ^ (row & GM)) << 3)];
    }
#pragma unroll
    for (int j = 0; j < 4; ++j) {
      int row = wc + (j << 4) + lr;
      b[j] = *(const bf16x8*)&sBT[row * K + ((kg ^ (row & GM)) << 3)];
    }
#pragma unroll
    for (int i = 0; i < 4; ++i)
#pragma unroll
      for (int j = 0; j < 4; ++j)
        c[i][j] = __builtin_amdgcn_mfma_f32_16x16x32_bf16(a[i], b[j], c[i][j], 0, 0, 0);
  }
}

// Single-block exclusive scan of deg[NN] -> cursor[NN]. 1024 threads, shfl scans.
__global__ __launch_bounds__(1024) void k_scan(const uint32_t* __restrict__ deg,
                                               uint32_t* __restrict__ cursor) {
  __shared__ uint32_t wsum[16];
  __shared__ uint32_t carry;
  const int t = threadIdx.x;
  const int lane = t & 63, wid = t >> 6;
  if (t == 0) carry = 0u;
  __syncthreads();
  for (int base = 0; base < NN; base += 1024) {
    int i = base + t;
    uint32_t v = (i < NN) ? deg[i] : 0u;
    uint32_t x = v;
#pragma unroll
    for (int off = 1; off < 64; off <<= 1) {
      uint32_t y = __shfl_up(x, off, 64);
      if (lane >= off) x += y;
    }
    if (lane == 63) wsum[wid] = x;
    __syncthreads();
    if (wid == 0 && lane < 16) {
      uint32_t s = wsum[lane];
#pragma unroll
      for (int off = 1; off < 16; off <<= 1) {
        uint32_t y = __shfl_up(s, off, 64);
        if (lane >= off) s += y;
      }
      wsum[lane] = s;  // inclusive
    }
    __syncthreads();
    uint32_t wexc = (wid == 0) ? 0u : wsum[wid - 1];
    uint32_t total = wsum[15];
    uint32_t c = carry;
    if (i < NN) cursor[i] = c + wexc + x - v;
    __syncthreads();
    if (t == 0) carry = c + total;
    __syncthreads();
  }
}

__global__ __launch_bounds__(256) void k_perm(const int* __restrict__ ei,
                                              uint32_t* __restrict__ cursor,
                                              int* __restrict__ perm,
                                              int* __restrict__ srcp,
                                              int* __restrict__ dstp) {
  int i = blockIdx.x * 256 + threadIdx.x;
  if (i < NE) {
    int s = ei[i], d = ei[NE + i];
    uint32_t pos = atomicAdd(&cursor[d], 1u);
    perm[pos] = i;
    srcp[pos] = s;
    dstp[pos] = d;
  }
}

// K1: Hp = bf16(hidden @ W_msg[0:128,:] + b_msg); also counts deg (fused k_deg)
__global__ __launch_bounds__(256) void k_hp(const float* __restrict__ hidden,
                                            const float* __restrict__ Wmsg,
                                            const float* __restrict__ bmsg,
                                            const int* __restrict__ ei,
                                            uint32_t* __restrict__ deg,
                                            u16* __restrict__ Hp) {
  __shared__ u16 sA[128 * 128];
  __shared__ u16 sBT[128 * 128];
  const int t = threadIdx.x;
  const int row0 = blockIdx.x << 7;
  // fused degree count (fire-and-forget atomics, overlap with staging)
  for (int i = blockIdx.x * 256 + t; i < NE; i += DEG_STRIDE)
    atomicAdd(&deg[ei[NE + i]], 1u);
#pragma unroll
  for (int it = 0; it < 16; ++it) {
    int li = t + (it << 8);
    int row = li >> 5, c4 = li & 31;
    int n = row0 + row;
    f32x4 v = {0.f, 0.f, 0.f, 0.f};
    if (n < NN) v = *(const f32x4*)(hidden + ((size_t)n << 7) + (c4 << 2));
    u16x4 b = {f2b(v[0]), f2b(v[1]), f2b(v[2]), f2b(v[3])};
    *(u16x4*)&sA[(row << 7) + ((((c4 >> 1) ^ (row & 15)) << 3) + ((c4 & 1) << 2))] = b;
  }
#pragma unroll
  for (int it = 0; it < 64; ++it) {
    int li = t + (it << 8);
    int k = li >> 7, d = li & 127;
    sBT[(d << 7) + ((((k >> 3) ^ (d & 15)) << 3) + (k & 7))] = f2b(Wmsg[li]);
  }
  __syncthreads();
  f32x4 c[4][4];
  mfma_tile<128, 15>(sA, sBT, t, c);
  const int lane = t & 63, w = t >> 6;
  const int wr = (w & 1) << 6, wc = (w >> 1) << 6;
  const int quad = lane >> 4, lr = lane & 15;
#pragma unroll
  for (int j = 0; j < 4; ++j) {
    int d = wc + (j << 4) + lr;
    float bias = bmsg[d];
#pragma unroll
    for (int i = 0; i < 4; ++i) {
      int nb = row0 + wr + (i << 4) + (quad << 2);
#pragma unroll
      for (int r = 0; r < 4; ++r) {
        int n = nb + r;
        if (n < NN) Hp[((size_t)n << 7) + d] = f2b(c[i][j][r] + bias);
      }
    }
  }
}

// K2 v2: 64-slot tiles, 4 blocks/CU. P = gather([attr|time], perm) @ Wc;
// msg = relu(P + Hp[src]) (Hp register-prefetched); segmented per-column
// reduction over dst runs: interior -> store, boundary -> atomic.
__global__ __launch_bounds__(256, 4) void k_edge2(const float* __restrict__ attr,
                                                  const float* __restrict__ tim,
                                                  const float* __restrict__ Wmsg,
                                                  const int* __restrict__ perm,
                                                  const int* __restrict__ srcp,
                                                  const int* __restrict__ dstp,
                                                  const u16* __restrict__ Hp,
                                                  float* __restrict__ acc) {
  __shared__ union {
    struct { u16 A[64 * 64]; u16 BT[128 * 64]; } ab; // 8 KB + 16 KB
    float C[64 * 128];                               // 32 KB
  } lds;
  __shared__ int sdst[64];
  const int t = threadIdx.x;
  const long e0 = (long)blockIdx.x << 6;

  // A gather: 8 threads per slot row (2 iters), f32x4 from attr and tim
#pragma unroll
  for (int it = 0; it < 2; ++it) {
    int li = t + (it << 8);
    int row = li >> 3, c4 = li & 7;
    long sg = e0 + row;
    f32x4 va = {0.f, 0.f, 0.f, 0.f}, vt = {0.f, 0.f, 0.f, 0.f};
    if (sg < NE) {
      int e = perm[sg];
      va = *(const f32x4*)(attr + ((size_t)e << 5) + (c4 << 2));
      vt = *(const f32x4*)(tim + ((size_t)e << 5) + (c4 << 2));
    }
    int g0 = c4 >> 1, h = (c4 & 1) << 2;
    u16x4 ba = {f2b(va[0]), f2b(va[1]), f2b(va[2]), f2b(va[3])};
    u16x4 bt = {f2b(vt[0]), f2b(vt[1]), f2b(vt[2]), f2b(vt[3])};
    *(u16x4*)&lds.ab.A[(row << 6) + (((g0 ^ (row & 7)) << 3) + h)] = ba;
    *(u16x4*)&lds.ab.A[(row << 6) + ((((g0 + 4) ^ (row & 7)) << 3) + h)] = bt;
  }
  // BT staging: W_msg rows 128..191 (64 k) x 128 d, vectorized global reads
#pragma unroll
  for (int it = 0; it < 8; ++it) {
    int li = t + (it << 8);               // 0..2047
    int k = li >> 5, d4 = (li & 31) << 2;
    f32x4 wv = *(const f32x4*)(Wmsg + 16384 + (k << 7) + d4);
#pragma unroll
    for (int q = 0; q < 4; ++q) {
      int d = d4 + q;
      lds.ab.BT[(d << 6) + ((((k >> 3) ^ (d & 7)) << 3) + (k & 7))] = f2b(wv[q]);
    }
  }
  // per-slot src/dst (coalesced) + Hp register prefetch: 4 threads/slot
  const int s = t >> 2, q = t & 3;
  const long sg1 = e0 + s;
  const bool v1 = sg1 < NE;
  int src = 0, dstn = -1;
  if (v1) { src = srcp[sg1]; dstn = dstp[sg1]; }
  u32x4 hp[4];
  if (v1) {
    const u32x4* hp4 = (const u32x4*)(Hp + ((size_t)src << 7) + (q << 5));
#pragma unroll
    for (int g = 0; g < 4; ++g) hp[g] = hp4[g];
  }
  if (q == 0) sdst[s] = v1 ? dstn : -1;
  __syncthreads();

  // MFMA: 64 slots x 128 cols, K=64. Each wave: rows 0-63 x cols w*32..+31.
  const int lane = t & 63, w = t >> 6;
  const int quad = lane >> 4, lr = lane & 15;
  f32x4 c[4][2];
#pragma unroll
  for (int i = 0; i < 4; ++i)
#pragma unroll
    for (int j = 0; j < 2; ++j) { f32x4 z = {0.f, 0.f, 0.f, 0.f}; c[i][j] = z; }
#pragma unroll
  for (int ks = 0; ks < 64; ks += 32) {
    const int kg = (ks >> 3) + quad;
    bf16x8 a[4], b[2];
#pragma unroll
    for (int i = 0; i < 4; ++i) {
      int row = (i << 4) + lr;
      a[i] = *(const bf16x8*)&lds.ab.A[(row << 6) + ((kg ^ (row & 7)) << 3)];
    }
#pragma unroll
    for (int j = 0; j < 2; ++j) {
      int col = (w << 5) + (j << 4) + lr;
      b[j] = *(const bf16x8*)&lds.ab.BT[(col << 6) + ((kg ^ (col & 7)) << 3)];
    }
#pragma unroll
    for (int i = 0; i < 4; ++i)
#pragma unroll
      for (int j = 0; j < 2; ++j)
        c[i][j] = __builtin_amdgcn_mfma_f32_16x16x32_bf16(a[i], b[j], c[i][j], 0, 0, 0);
  }
  __syncthreads();
  // C -> LDS (swizzled)
#pragma unroll
  for (int i = 0; i < 4; ++i)
#pragma unroll
    for (int j = 0; j < 2; ++j)
#pragma unroll
      for (int r = 0; r < 4; ++r) {
        int row = (i << 4) + (quad << 2) + r;
        int col = (w << 5) + (j << 4) + lr;
        lds.C[(row << 7) + ((((col >> 2) ^ (row & 31)) << 2) + (col & 3))] = c[i][j][r];
      }
  __syncthreads();
  // stage 1: msg = relu(P + Hp[src]) in place; thread (s,q) owns cols q*32..+31
  if (v1) {
#pragma unroll
    for (int g = 0; g < 8; ++g) {
      int cb = (q << 5) + (g << 2);
      float* p = &lds.C[(s << 7) + ((((cb >> 2) ^ (s & 31)) << 2))];
      f32x4 cv = *(const f32x4*)p;
      uint32_t w0 = hp[g >> 1][(g & 1) << 1];
      uint32_t w1 = hp[g >> 1][((g & 1) << 1) + 1];
      cv[0] = fmaxf(cv[0] + b2f(w0 & 0xffffu), 0.f);
      cv[1] = fmaxf(cv[1] + b2f(w0 >> 16), 0.f);
      cv[2] = fmaxf(cv[2] + b2f(w1 & 0xffffu), 0.f);
      cv[3] = fmaxf(cv[3] + b2f(w1 >> 16), 0.f);
      *(f32x4*)p = cv;
    }
  }
  __syncthreads();
  // stage 2: per-column segmented reduction over dst runs
  if (t < 128) {
    const int col = t;
    int cur = sdst[0];
    float sum = 0.f;
    int runstart = 0;
    for (int ss = 0; ss < SPB; ++ss) {
      int d = sdst[ss];
      if (d != cur) {
        if (cur >= 0) {
          float* p = acc + ((size_t)cur << 7) + col;
          if (runstart == 0) unsafeAtomicAdd(p, sum);
          else *p = sum;
        }
        cur = d; sum = 0.f; runstart = ss;
      }
      sum += lds.C[(ss << 7) + ((((col >> 2) ^ (ss & 31)) << 2) + (col & 3))];
    }
    if (cur >= 0) unsafeAtomicAdd(acc + ((size_t)cur << 7) + col, sum);
  }
}

// K3 (in-place): out = dropout(relu(LN((acc+boundary) @ W_lin + b_lin)))
__global__ __launch_bounds__(256) void k_out(float* accout,
                                             const float* __restrict__ bnd,
                                             const float* __restrict__ Wlin,
                                             const float* __restrict__ blin,
                                             const float* __restrict__ gam,
                                             const float* __restrict__ bet) {
  __shared__ union {
    struct { u16 A[128 * 128]; u16 BT[128 * 128]; } ab;
    float C[128 * 128];
  } lds;
  const int t = threadIdx.x;
  const int row0 = blockIdx.x << 7;
#pragma unroll
  for (int it = 0; it < 16; ++it) {
    int li = t + (it << 8);
    int row = li >> 5, c4 = li & 31;
    int n = row0 + row;
    f32x4 v = {0.f, 0.f, 0.f, 0.f};
    if (n < NN) {
      f32x4 a = *(const f32x4*)(accout + ((size_t)n << 7) + (c4 << 2));
      f32x4 b = *(const f32x4*)(bnd + ((size_t)n << 7) + (c4 << 2));
      v = a + b;
    }
    u16x4 bb = {f2b(v[0]), f2b(v[1]), f2b(v[2]), f2b(v[3])};
    *(u16x4*)&lds.ab.A[(row << 7) + ((((c4 >> 1) ^ (row & 15)) << 3) + ((c4 & 1) << 2))] = bb;
  }
#pragma unroll
  for (int it = 0; it < 64; ++it) {
    int li = t + (it << 8);
    int k = li >> 7, d = li & 127;
    lds.ab.BT[(d << 7) + ((((k >> 3) ^ (d & 15)) << 3) + (k & 7))] = f2b(Wlin[li]);
  }
  __syncthreads();
  f32x4 c[4][4];
  mfma_tile<128, 15>(lds.ab.A, lds.ab.BT, t, c);
  __syncthreads();
  {
    const int lane = t & 63, w = t >> 6;
    const int wr = (w & 1) << 6, wc = (w >> 1) << 6;
    const int quad = lane >> 4, lr = lane & 15;
#pragma unroll
    for (int i = 0; i < 4; ++i)
#pragma unroll
      for (int j = 0; j < 4; ++j)
#pragma unroll
        for (int r = 0; r < 4; ++r) {
          int row = wr + (i << 4) + (quad << 2) + r;
          int col = wc + (j << 4) + lr;
          lds.C[(row << 7) + ((((col >> 2) ^ (row & 31)) << 2) + (col & 3))] = c[i][j][r];
        }
  }
  __syncthreads();
  const int row = t >> 1, off = (t & 1) << 6;
  const int n = row0 + row;
  float s1 = 0.f, s2 = 0.f;
  if (n < NN) {
    for (int g = 0; g < 16; ++g) {
      int cb = off + (g << 2);
      f32x4 cv = *(const f32x4*)&lds.C[(row << 7) + (((cb >> 2) ^ (row & 31)) << 2)];
#pragma unroll
      for (int q = 0; q < 4; ++q) {
        float x = cv[q] + blin[cb + q];
        s1 += x; s2 += x * x;
      }
    }
  }
  s1 += __shfl_xor(s1, 1, 64);
  s2 += __shfl_xor(s2, 1, 64);
  if (n < NN) {
    const float mean = s1 * 0.0078125f;
    const float var = s2 * 0.0078125f - mean * mean;
    const float inv = 1.0f / sqrtf(var + 1e-5f);
    for (int g = 0; g < 16; ++g) {
      int cb = off + (g << 2);
      f32x4 cv = *(const f32x4*)&lds.C[(row << 7) + (((cb >> 2) ^ (row & 31)) << 2)];
#pragma unroll
      for (int q = 0; q < 4; ++q) {
        int d = cb + q;
        float x = cv[q] + blin[d];
        float y = (x - mean) * inv * gam[d] + bet[d];
        y = fmaxf(y, 0.f);
        uint32_t jj = ((uint32_t)n << 7) + (uint32_t)d;
        accout[((size_t)n << 7) + d] = jax_keep(jj) ? (y * (1.0f / 0.9f)) : 0.0f;
      }
    }
  }
}

extern "C" void kernel_launch(void* const* d_in, const int* in_sizes, int n_in,
                              void* d_out, int out_size, void* d_ws, size_t ws_size,
                              hipStream_t stream) {
  (void)in_sizes; (void)n_in; (void)out_size; (void)ws_size;
  const float* hidden = (const float*)d_in[0];
  const int*   ei     = (const int*)d_in[1];
  const float* attr   = (const float*)d_in[2];
  const float* tim    = (const float*)d_in[3];
  const float* bnd    = (const float*)d_in[4];
  const float* Wmsg   = (const float*)d_in[5];
  const float* bmsg   = (const float*)d_in[6];
  const float* Wlin   = (const float*)d_in[7];
  const float* blin   = (const float*)d_in[8];
  const float* gam    = (const float*)d_in[9];
  const float* bet    = (const float*)d_in[10];

  float* acc = (float*)d_out;  // [N,128] f32 accumulator, finalized in-place by k_out

  char* ws = (char*)d_ws;
  u16*      Hp     = (u16*)(ws + 0);              // 12,800,000 B
  uint32_t* deg    = (uint32_t*)(ws + 12800000);  //    200,000 B
  uint32_t* cursor = (uint32_t*)(ws + 13000064);  //    200,000 B
  int*      perm   = (int*)(ws + 13200128);       //  2,000,000 B
  int*      srcp   = (int*)(ws + 15200128);       //  2,000,000 B
  int*      dstp   = (int*)(ws + 17200128);       //  2,000,000 B

  hipMemsetAsync(deg, 0, (size_t)NN * 4, stream);
  hipMemsetAsync(acc, 0, (size_t)NN * 128 * 4, stream);

  k_hp   <<<dim3(HP_BLOCKS), dim3(256), 0, stream>>>(hidden, Wmsg, bmsg, ei, deg, Hp);
  k_scan <<<dim3(1), dim3(1024), 0, stream>>>(deg, cursor);
  k_perm <<<dim3((NE + 255) / 256), dim3(256), 0, stream>>>(ei, cursor, perm, srcp, dstp);
  k_edge2<<<dim3((NE + SPB - 1) / SPB), dim3(256), 0, stream>>>(attr, tim, Wmsg, perm, srcp, dstp, Hp, acc);
  k_out  <<<dim3((NN + 127) / 128), dim3(256), 0, stream>>>(acc, bnd, Wlin, blin, gam, bet);
}

// Round 5
// 387.708 us; speedup vs baseline: 1.2198x; 1.2198x over previous
//
#include <hip/hip_runtime.h>
#include <stdint.h>

#define NN 50000
#define NE 500000
#define NEPAD 500032              // NE rounded up to 64 (7813 * 64)
#define SPB 64
#define HP_BLOCKS ((NN + 127) / 128)          // 391
#define DEG_STRIDE (HP_BLOCKS * 256)          // 100096
#define NBLK_N ((NN + 255) / 256)             // 196

typedef short bf16x8 __attribute__((ext_vector_type(8)));
typedef float f32x4 __attribute__((ext_vector_type(4)));
typedef unsigned short u16;
typedef unsigned short u16x4 __attribute__((ext_vector_type(4)));
typedef unsigned int u32x4 __attribute__((ext_vector_type(4)));

__device__ __forceinline__ u16 f2b(float x) {
  uint32_t u = __builtin_bit_cast(uint32_t, x);
  return (u16)((u + 0x7fffu + ((u >> 16) & 1u)) >> 16);
}
__device__ __forceinline__ float b2f(uint32_t lo16) {
  return __builtin_bit_cast(float, lo16 << 16);
}

// JAX threefry2x32, key = jax.random.key(42) -> (0, 42)
__device__ __forceinline__ void threefry(uint32_t x0, uint32_t x1,
                                         uint32_t& o0, uint32_t& o1) {
  const uint32_t k0 = 0u, k1 = 42u, k2 = 0u ^ 42u ^ 0x1BD11BDAu;
  x0 += k0; x1 += k1;
#define TFR(r) { x0 += x1; x1 = (x1 << r) | (x1 >> (32 - r)); x1 ^= x0; }
  TFR(13) TFR(15) TFR(26) TFR(6)
  x0 += k1; x1 += k2 + 1u;
  TFR(17) TFR(29) TFR(16) TFR(24)
  x0 += k2; x1 += k0 + 2u;
  TFR(13) TFR(15) TFR(26) TFR(6)
  x0 += k0; x1 += k1 + 3u;
  TFR(17) TFR(29) TFR(16) TFR(24)
  x0 += k1; x1 += k2 + 4u;
  TFR(13) TFR(15) TFR(26) TFR(6)
  x0 += k2; x1 += k0 + 5u;
#undef TFR
  o0 = x0; o1 = x1;
}

__device__ __forceinline__ bool jax_keep(uint32_t j) {
  uint32_t o0, o1;
  threefry(0u, j, o0, o1);
  uint32_t bits = o0 ^ o1;
  float u = __builtin_bit_cast(float, (bits >> 9) | 0x3f800000u) - 1.0f;
  return u < 0.9f;
}

// 128x128 tile, 4 waves each 64x64, K=128 (k_hp / k_out).
template <int K, int GM>
__device__ __forceinline__ void mfma_tile(const u16* sA, const u16* sBT,
                                          int t, f32x4 (&c)[4][4]) {
  const int lane = t & 63, w = t >> 6;
  const int wr = (w & 1) << 6, wc = (w >> 1) << 6;
  const int quad = lane >> 4, lr = lane & 15;
#pragma unroll
  for (int i = 0; i < 4; ++i)
#pragma unroll
    for (int j = 0; j < 4; ++j) { f32x4 z = {0.f, 0.f, 0.f, 0.f}; c[i][j] = z; }
#pragma unroll
  for (int ks = 0; ks < K; ks += 32) {
    const int kg = (ks >> 3) + quad;
    bf16x8 a[4], b[4];
#pragma unroll
    for (int i = 0; i < 4; ++i) {
      int row = wr + (i << 4) + lr;
      a[i] = *(const bf16x8*)&sA[row * K + ((kg ^ (row & GM)) << 3)];
    }
#pragma unroll
    for (int j = 0; j < 4; ++j) {
      int row = wc + (j << 4) + lr;
      b[j] = *(const bf16x8*)&sBT[row * K + ((kg ^ (row & GM)) << 3)];
    }
#pragma unroll
    for (int i = 0; i < 4; ++i)
#pragma unroll
      for (int j = 0; j < 4; ++j)
        c[i][j] = __builtin_amdgcn_mfma_f32_16x16x32_bf16(a[i], b[j], c[i][j], 0, 0, 0);
  }
}

// ---- hierarchical scan (parallel; round-3 proven) ----
__global__ __launch_bounds__(256) void k_scan1(const uint32_t* __restrict__ deg,
                                               uint32_t* __restrict__ ex,
                                               uint32_t* __restrict__ bsum) {
  __shared__ uint32_t s[256];
  int t = threadIdx.x;
  int i = blockIdx.x * 256 + t;
  uint32_t v = (i < NN) ? deg[i] : 0u;
  s[t] = v;
  __syncthreads();
#pragma unroll
  for (int off = 1; off < 256; off <<= 1) {
    uint32_t y = (t >= off) ? s[t - off] : 0u;
    __syncthreads();
    s[t] += y;
    __syncthreads();
  }
  if (i < NN) ex[i] = s[t] - v;
  if (t == 255) bsum[blockIdx.x] = s[255];
}

__global__ __launch_bounds__(256) void k_scan2(const uint32_t* __restrict__ bsum,
                                               uint32_t* __restrict__ boff) {
  __shared__ uint32_t s[256];
  int t = threadIdx.x;
  uint32_t v = (t < NBLK_N) ? bsum[t] : 0u;
  s[t] = v;
  __syncthreads();
#pragma unroll
  for (int off = 1; off < 256; off <<= 1) {
    uint32_t y = (t >= off) ? s[t - off] : 0u;
    __syncthreads();
    s[t] += y;
    __syncthreads();
  }
  boff[t] = s[t] - v;
}

__global__ __launch_bounds__(256) void k_scan3(const uint32_t* __restrict__ ex,
                                               const uint32_t* __restrict__ boff,
                                               uint32_t* __restrict__ cursor) {
  int i = blockIdx.x * 256 + threadIdx.x;
  if (i < NN) cursor[i] = ex[i] + boff[blockIdx.x];
}

// k_perm SORTED: 8 threads/edge; scatter bf16 [attr|tim] row to sorted slot.
__global__ __launch_bounds__(256) void k_perm_s(const int* __restrict__ ei,
                                                const float* __restrict__ attr,
                                                const float* __restrict__ tim,
                                                uint32_t* __restrict__ cursor,
                                                u16* __restrict__ Asorted,
                                                int* __restrict__ srcp,
                                                int* __restrict__ dstp) {
  const int t = threadIdx.x;
  const int j = t & 7;
  const long e = (long)blockIdx.x * 32 + (t >> 3);
  const bool v = e < NE;
  int src = 0, dst = 0;
  uint32_t pos = 0;
  if (v && j == 0) {
    src = ei[e];
    dst = ei[NE + e];
    pos = atomicAdd(&cursor[dst], 1u);
  }
  pos = __shfl(pos, 0, 8);
  src = __shfl(src, 0, 8);
  dst = __shfl(dst, 0, 8);
  if (v) {
    f32x4 va = *(const f32x4*)(attr + ((size_t)e << 5) + (j << 2));
    f32x4 vt = *(const f32x4*)(tim + ((size_t)e << 5) + (j << 2));
    u16x4 ba = {f2b(va[0]), f2b(va[1]), f2b(va[2]), f2b(va[3])};
    u16x4 bt = {f2b(vt[0]), f2b(vt[1]), f2b(vt[2]), f2b(vt[3])};
    *(u16x4*)&Asorted[((size_t)pos << 6) + (j << 2)] = ba;
    *(u16x4*)&Asorted[((size_t)pos << 6) + 32 + (j << 2)] = bt;
    if (j == 0) { srcp[pos] = src; dstp[pos] = dst; }
  }
}

// k_perm fallback: permutation index only
__global__ __launch_bounds__(256) void k_perm_f(const int* __restrict__ ei,
                                                uint32_t* __restrict__ cursor,
                                                int* __restrict__ perm,
                                                int* __restrict__ srcp,
                                                int* __restrict__ dstp) {
  int i = blockIdx.x * 256 + threadIdx.x;
  if (i < NE) {
    int s = ei[i], d = ei[NE + i];
    uint32_t pos = atomicAdd(&cursor[d], 1u);
    perm[pos] = i;
    srcp[pos] = s;
    dstp[pos] = d;
  }
}

// K1: Hp = bf16(hidden @ W_msg[0:128,:] + b_msg); fused deg count;
// block 0 also builds WcImg[d][k] = bf16(W_msg[128+k][d])  (64x128 -> 16 KB)
__global__ __launch_bounds__(256) void k_hp(const float* __restrict__ hidden,
                                            const float* __restrict__ Wmsg,
                                            const float* __restrict__ bmsg,
                                            const int* __restrict__ ei,
                                            uint32_t* __restrict__ deg,
                                            u16* __restrict__ Hp,
                                            u16* __restrict__ WcImg) {
  __shared__ u16 sA[128 * 128];
  __shared__ u16 sBT[128 * 128];
  const int t = threadIdx.x;
  const int row0 = blockIdx.x << 7;
  for (int i = blockIdx.x * 256 + t; i < NE; i += DEG_STRIDE)
    atomicAdd(&deg[ei[NE + i]], 1u);
  if (blockIdx.x == 0) {
#pragma unroll
    for (int it = 0; it < 32; ++it) {
      int li = t + (it << 8);           // 0..8191
      int k = li >> 7, d = li & 127;
      WcImg[(d << 6) + k] = f2b(Wmsg[16384 + li]);
    }
  }
#pragma unroll
  for (int it = 0; it < 16; ++it) {
    int li = t + (it << 8);
    int row = li >> 5, c4 = li & 31;
    int n = row0 + row;
    f32x4 v = {0.f, 0.f, 0.f, 0.f};
    if (n < NN) v = *(const f32x4*)(hidden + ((size_t)n << 7) + (c4 << 2));
    u16x4 b = {f2b(v[0]), f2b(v[1]), f2b(v[2]), f2b(v[3])};
    *(u16x4*)&sA[(row << 7) + ((((c4 >> 1) ^ (row & 15)) << 3) + ((c4 & 1) << 2))] = b;
  }
#pragma unroll
  for (int it = 0; it < 64; ++it) {
    int li = t + (it << 8);
    int k = li >> 7, d = li & 127;
    sBT[(d << 7) + ((((k >> 3) ^ (d & 15)) << 3) + (k & 7))] = f2b(Wmsg[li]);
  }
  __syncthreads();
  f32x4 c[4][4];
  mfma_tile<128, 15>(sA, sBT, t, c);
  const int lane = t & 63, w = t >> 6;
  const int wr = (w & 1) << 6, wc = (w >> 1) << 6;
  const int quad = lane >> 4, lr = lane & 15;
#pragma unroll
  for (int j = 0; j < 4; ++j) {
    int d = wc + (j << 4) + lr;
    float bias = bmsg[d];
#pragma unroll
    for (int i = 0; i < 4; ++i) {
      int nb = row0 + wr + (i << 4) + (quad << 2);
#pragma unroll
      for (int r = 0; r < 4; ++r) {
        int n = nb + r;
        if (n < NN) Hp[((size_t)n << 7) + d] = f2b(c[i][j][r] + bias);
      }
    }
  }
}

// K2 v3: B from global WcImg (L1-hot); A from Asorted (SORTED) or
// LDS-staged perm gather (fallback). LDS = C tile only (union w/ A).
template <bool SORTED>
__global__ __launch_bounds__(256, 4) void k_edge3(const float* __restrict__ attr,
                                                  const float* __restrict__ tim,
                                                  const int* __restrict__ perm,
                                                  const u16* __restrict__ Asorted,
                                                  const u16* __restrict__ WcImg,
                                                  const int* __restrict__ srcp,
                                                  const int* __restrict__ dstp,
                                                  const u16* __restrict__ Hp,
                                                  float* __restrict__ acc) {
  __shared__ union { u16 A[64 * 64]; float C[64 * 128]; } lds;  // 32 KB
  __shared__ int sdst[64];
  const int t = threadIdx.x;
  const long e0 = (long)blockIdx.x << 6;

  if (!SORTED) {
#pragma unroll
    for (int it = 0; it < 2; ++it) {
      int li = t + (it << 8);
      int row = li >> 3, c4 = li & 7;
      long sg = e0 + row;
      f32x4 va = {0.f, 0.f, 0.f, 0.f}, vt = {0.f, 0.f, 0.f, 0.f};
      if (sg < NE) {
        int e = perm[sg];
        va = *(const f32x4*)(attr + ((size_t)e << 5) + (c4 << 2));
        vt = *(const f32x4*)(tim + ((size_t)e << 5) + (c4 << 2));
      }
      int g0 = c4 >> 1, h = (c4 & 1) << 2;
      u16x4 ba = {f2b(va[0]), f2b(va[1]), f2b(va[2]), f2b(va[3])};
      u16x4 bt = {f2b(vt[0]), f2b(vt[1]), f2b(vt[2]), f2b(vt[3])};
      *(u16x4*)&lds.A[(row << 6) + (((g0 ^ (row & 7)) << 3) + h)] = ba;
      *(u16x4*)&lds.A[(row << 6) + ((((g0 + 4) ^ (row & 7)) << 3) + h)] = bt;
    }
  }
  // per-slot src/dst + Hp register prefetch: 4 threads/slot
  const int s = t >> 2, q = t & 3;
  const long sg1 = e0 + s;
  const bool v1 = sg1 < NE;
  int src = 0, dstn = -1;
  if (v1) { src = srcp[sg1]; dstn = dstp[sg1]; }
  u32x4 hp[4];
  if (v1) {
    const u32x4* hp4 = (const u32x4*)(Hp + ((size_t)src << 7) + (q << 5));
#pragma unroll
    for (int g = 0; g < 4; ++g) hp[g] = hp4[g];
  }
  if (q == 0) sdst[s] = v1 ? dstn : -1;
  __syncthreads();

  // MFMA: 64 slots x 128 cols, K=64. Wave w: cols w*32..+31.
  const int lane = t & 63, w = t >> 6;
  const int quad = lane >> 4, lr = lane & 15;
  f32x4 c[4][2];
#pragma unroll
  for (int i = 0; i < 4; ++i)
#pragma unroll
    for (int j = 0; j < 2; ++j) { f32x4 z = {0.f, 0.f, 0.f, 0.f}; c[i][j] = z; }
#pragma unroll
  for (int ks = 0; ks < 64; ks += 32) {
    const int gi = (ks >> 3) + quad;
    bf16x8 a[4], b[2];
#pragma unroll
    for (int i = 0; i < 4; ++i) {
      int row = (i << 4) + lr;
      if (SORTED)
        a[i] = *(const bf16x8*)&Asorted[((size_t)(e0 + row) << 6) + (gi << 3)];
      else
        a[i] = *(const bf16x8*)&lds.A[(row << 6) + ((gi ^ (row & 7)) << 3)];
    }
#pragma unroll
    for (int j = 0; j < 2; ++j) {
      int col = (w << 5) + (j << 4) + lr;
      b[j] = *(const bf16x8*)&WcImg[(col << 6) + (gi << 3)];
    }
#pragma unroll
    for (int i = 0; i < 4; ++i)
#pragma unroll
      for (int j = 0; j < 2; ++j)
        c[i][j] = __builtin_amdgcn_mfma_f32_16x16x32_bf16(a[i], b[j], c[i][j], 0, 0, 0);
  }
  __syncthreads();  // A (fallback) fully consumed before C overwrites LDS
#pragma unroll
  for (int i = 0; i < 4; ++i)
#pragma unroll
    for (int j = 0; j < 2; ++j)
#pragma unroll
      for (int r = 0; r < 4; ++r) {
        int row = (i << 4) + (quad << 2) + r;
        int col = (w << 5) + (j << 4) + lr;
        lds.C[(row << 7) + ((((col >> 2) ^ (row & 31)) << 2) + (col & 3))] = c[i][j][r];
      }
  __syncthreads();
  // stage 1: msg = relu(P + Hp[src]); thread (s,q) owns cols q*32..+31
  if (v1) {
#pragma unroll
    for (int g = 0; g < 8; ++g) {
      int cb = (q << 5) + (g << 2);
      float* p = &lds.C[(s << 7) + ((((cb >> 2) ^ (s & 31)) << 2))];
      f32x4 cv = *(const f32x4*)p;
      uint32_t w0 = hp[g >> 1][(g & 1) << 1];
      uint32_t w1 = hp[g >> 1][((g & 1) << 1) + 1];
      cv[0] = fmaxf(cv[0] + b2f(w0 & 0xffffu), 0.f);
      cv[1] = fmaxf(cv[1] + b2f(w0 >> 16), 0.f);
      cv[2] = fmaxf(cv[2] + b2f(w1 & 0xffffu), 0.f);
      cv[3] = fmaxf(cv[3] + b2f(w1 >> 16), 0.f);
      *(f32x4*)p = cv;
    }
  }
  __syncthreads();
  // stage 2: segmented reduction, 2 halves x 128 cols (depth 32)
  {
    const int col = t & 127, half = t >> 7;
    const int beg = half << 5, end = beg + 32;
    int cur = sdst[beg];
    float sum = 0.f;
    int runstart = beg;
    for (int ss = beg; ss < end; ++ss) {
      int d = sdst[ss];
      if (d != cur) {
        if (cur >= 0) {
          float* p = acc + ((size_t)cur << 7) + col;
          if (runstart == beg) unsafeAtomicAdd(p, sum);
          else *p = sum;
        }
        cur = d; sum = 0.f; runstart = ss;
      }
      sum += lds.C[(ss << 7) + ((((col >> 2) ^ (ss & 31)) << 2) + (col & 3))];
    }
    if (cur >= 0) unsafeAtomicAdd(acc + ((size_t)cur << 7) + col, sum);
  }
}

// K3 (in-place): out = dropout(relu(LN((acc+boundary) @ W_lin + b_lin)))
__global__ __launch_bounds__(256) void k_out(float* accout,
                                             const float* __restrict__ bnd,
                                             const float* __restrict__ Wlin,
                                             const float* __restrict__ blin,
                                             const float* __restrict__ gam,
                                             const float* __restrict__ bet) {
  __shared__ union {
    struct { u16 A[128 * 128]; u16 BT[128 * 128]; } ab;
    float C[128 * 128];
  } lds;
  const int t = threadIdx.x;
  const int row0 = blockIdx.x << 7;
#pragma unroll
  for (int it = 0; it < 16; ++it) {
    int li = t + (it << 8);
    int row = li >> 5, c4 = li & 31;
    int n = row0 + row;
    f32x4 v = {0.f, 0.f, 0.f, 0.f};
    if (n < NN) {
      f32x4 a = *(const f32x4*)(accout + ((size_t)n << 7) + (c4 << 2));
      f32x4 b = *(const f32x4*)(bnd + ((size_t)n << 7) + (c4 << 2));
      v = a + b;
    }
    u16x4 bb = {f2b(v[0]), f2b(v[1]), f2b(v[2]), f2b(v[3])};
    *(u16x4*)&lds.ab.A[(row << 7) + ((((c4 >> 1) ^ (row & 15)) << 3) + ((c4 & 1) << 2))] = bb;
  }
#pragma unroll
  for (int it = 0; it < 64; ++it) {
    int li = t + (it << 8);
    int k = li >> 7, d = li & 127;
    lds.ab.BT[(d << 7) + ((((k >> 3) ^ (d & 15)) << 3) + (k & 7))] = f2b(Wlin[li]);
  }
  __syncthreads();
  f32x4 c[4][4];
  mfma_tile<128, 15>(lds.ab.A, lds.ab.BT, t, c);
  __syncthreads();
  {
    const int lane = t & 63, w = t >> 6;
    const int wr = (w & 1) << 6, wc = (w >> 1) << 6;
    const int quad = lane >> 4, lr = lane & 15;
#pragma unroll
    for (int i = 0; i < 4; ++i)
#pragma unroll
      for (int j = 0; j < 4; ++j)
#pragma unroll
        for (int r = 0; r < 4; ++r) {
          int row = wr + (i << 4) + (quad << 2) + r;
          int col = wc + (j << 4) + lr;
          lds.C[(row << 7) + ((((col >> 2) ^ (row & 31)) << 2) + (col & 3))] = c[i][j][r];
        }
  }
  __syncthreads();
  const int row = t >> 1, off = (t & 1) << 6;
  const int n = row0 + row;
  float s1 = 0.f, s2 = 0.f;
  if (n < NN) {
    for (int g = 0; g < 16; ++g) {
      int cb = off + (g << 2);
      f32x4 cv = *(const f32x4*)&lds.C[(row << 7) + (((cb >> 2) ^ (row & 31)) << 2)];
#pragma unroll
      for (int q = 0; q < 4; ++q) {
        float x = cv[q] + blin[cb + q];
        s1 += x; s2 += x * x;
      }
    }
  }
  s1 += __shfl_xor(s1, 1, 64);
  s2 += __shfl_xor(s2, 1, 64);
  if (n < NN) {
    const float mean = s1 * 0.0078125f;
    const float var = s2 * 0.0078125f - mean * mean;
    const float inv = 1.0f / sqrtf(var + 1e-5f);
    for (int g = 0; g < 16; ++g) {
      int cb = off + (g << 2);
      f32x4 cv = *(const f32x4*)&lds.C[(row << 7) + (((cb >> 2) ^ (row & 31)) << 2)];
#pragma unroll
      for (int q = 0; q < 4; ++q) {
        int d = cb + q;
        float x = cv[q] + blin[d];
        float y = (x - mean) * inv * gam[d] + bet[d];
        y = fmaxf(y, 0.f);
        uint32_t jj = ((uint32_t)n << 7) + (uint32_t)d;
        accout[((size_t)n << 7) + d] = jax_keep(jj) ? (y * (1.0f / 0.9f)) : 0.0f;
      }
    }
  }
}

extern "C" void kernel_launch(void* const* d_in, const int* in_sizes, int n_in,
                              void* d_out, int out_size, void* d_ws, size_t ws_size,
                              hipStream_t stream) {
  (void)in_sizes; (void)n_in; (void)out_size;
  const float* hidden = (const float*)d_in[0];
  const int*   ei     = (const int*)d_in[1];
  const float* attr   = (const float*)d_in[2];
  const float* tim    = (const float*)d_in[3];
  const float* bnd    = (const float*)d_in[4];
  const float* Wmsg   = (const float*)d_in[5];
  const float* bmsg   = (const float*)d_in[6];
  const float* Wlin   = (const float*)d_in[7];
  const float* blin   = (const float*)d_in[8];
  const float* gam    = (const float*)d_in[9];
  const float* bet    = (const float*)d_in[10];

  float* acc = (float*)d_out;  // [N,128] f32 accumulator, finalized in-place

  char* ws = (char*)d_ws;
  u16*      Hp     = (u16*)(ws + 0);              // 12,800,000
  u16*      WcImg  = (u16*)(ws + 12800000);       //     16,384
  uint32_t* deg    = (uint32_t*)(ws + 12816384);  //    200,000
  uint32_t* cursor = (uint32_t*)(ws + 13016384);  //    200,000
  uint32_t* bsum   = (uint32_t*)(ws + 13216384);  //      1,024
  uint32_t* boff   = (uint32_t*)(ws + 13217408);  //      1,024
  uint32_t* ex     = (uint32_t*)(ws + 13218432);  //    200,000
  int*      srcp   = (int*)(ws + 13418432);       //  2,000,000
  int*      dstp   = (int*)(ws + 15418432);       //  2,000,000
  u16*      Asort  = (u16*)(ws + 17418432);       // 64,004,096 (sorted path)
  int*      perm   = (int*)(ws + 17418432);       //  2,000,000 (fallback)
  const bool sorted = ws_size >= (size_t)(17418432 + (size_t)NEPAD * 64 * 2);

  hipMemsetAsync(deg, 0, (size_t)NN * 4, stream);
  hipMemsetAsync(acc, 0, (size_t)NN * 128 * 4, stream);

  k_hp   <<<dim3(HP_BLOCKS), dim3(256), 0, stream>>>(hidden, Wmsg, bmsg, ei, deg, Hp, WcImg);
  k_scan1<<<dim3(NBLK_N), dim3(256), 0, stream>>>(deg, ex, bsum);
  k_scan2<<<dim3(1), dim3(256), 0, stream>>>(bsum, boff);
  k_scan3<<<dim3(NBLK_N), dim3(256), 0, stream>>>(ex, boff, cursor);
  if (sorted) {
    k_perm_s<<<dim3((NE + 31) / 32), dim3(256), 0, stream>>>(ei, attr, tim, cursor, Asort, srcp, dstp);
    k_edge3<true><<<dim3(NEPAD / SPB), dim3(256), 0, stream>>>(attr, tim, nullptr, Asort, WcImg, srcp, dstp, Hp, acc);
  } else {
    k_perm_f<<<dim3((NE + 255) / 256), dim3(256), 0, stream>>>(ei, cursor, perm, srcp, dstp);
    k_edge3<false><<<dim3(NEPAD / SPB), dim3(256), 0, stream>>>(attr, tim, perm, nullptr, WcImg, srcp, dstp, Hp, acc);
  }
  k_out  <<<dim3((NN + 127) / 128), dim3(256), 0, stream>>>(acc, bnd, Wlin, blin, gam, bet);
}

// Round 6
// 369.759 us; speedup vs baseline: 1.2790x; 1.0485x over previous
//
#include <hip/hip_runtime.h>
#include <stdint.h>

#define NN 50000
#define NE 500000
#define NEPAD 500032              // NE rounded up to 64
#define SPB 64
#define NT_BLOCKS ((NN + 63) / 64)            // 782 (k_hp / k_out grids)
#define DEG_STRIDE (NT_BLOCKS * 256)          // 200192
#define NBLK_N ((NN + 255) / 256)             // 196

typedef short bf16x8 __attribute__((ext_vector_type(8)));
typedef float f32x4 __attribute__((ext_vector_type(4)));
typedef unsigned short u16;
typedef unsigned short u16x4 __attribute__((ext_vector_type(4)));
typedef unsigned int u32x4 __attribute__((ext_vector_type(4)));

__device__ __forceinline__ u16 f2b(float x) {
  uint32_t u = __builtin_bit_cast(uint32_t, x);
  return (u16)((u + 0x7fffu + ((u >> 16) & 1u)) >> 16);
}
__device__ __forceinline__ float b2f(uint32_t lo16) {
  return __builtin_bit_cast(float, lo16 << 16);
}

// JAX threefry2x32, key = jax.random.key(42) -> (0, 42)
__device__ __forceinline__ void threefry(uint32_t x0, uint32_t x1,
                                         uint32_t& o0, uint32_t& o1) {
  const uint32_t k0 = 0u, k1 = 42u, k2 = 0u ^ 42u ^ 0x1BD11BDAu;
  x0 += k0; x1 += k1;
#define TFR(r) { x0 += x1; x1 = (x1 << r) | (x1 >> (32 - r)); x1 ^= x0; }
  TFR(13) TFR(15) TFR(26) TFR(6)
  x0 += k1; x1 += k2 + 1u;
  TFR(17) TFR(29) TFR(16) TFR(24)
  x0 += k2; x1 += k0 + 2u;
  TFR(13) TFR(15) TFR(26) TFR(6)
  x0 += k0; x1 += k1 + 3u;
  TFR(17) TFR(29) TFR(16) TFR(24)
  x0 += k1; x1 += k2 + 4u;
  TFR(13) TFR(15) TFR(26) TFR(6)
  x0 += k2; x1 += k0 + 5u;
#undef TFR
  o0 = x0; o1 = x1;
}

__device__ __forceinline__ bool jax_keep(uint32_t j) {
  uint32_t o0, o1;
  threefry(0u, j, o0, o1);
  uint32_t bits = o0 ^ o1;
  float u = __builtin_bit_cast(float, (bits >> 9) | 0x3f800000u) - 1.0f;
  return u < 0.9f;
}

// ---- weight images: W*Img[d][k] = bf16(W[k][d]) (transposed, B-operand ready)
__global__ __launch_bounds__(256) void k_prep(const float* __restrict__ Wmsg,
                                              const float* __restrict__ Wlin,
                                              u16* __restrict__ WhImg,
                                              u16* __restrict__ WcImg,
                                              u16* __restrict__ WlImg) {
  const int t = threadIdx.x, b = blockIdx.x;
  if (b == 0) {
#pragma unroll
    for (int it = 0; it < 16; ++it) {
      int g = t + (it << 8);
      int d = g >> 5, k4 = (g & 31) << 2;
      u16x4 v = {f2b(Wmsg[(k4 + 0) * 128 + d]), f2b(Wmsg[(k4 + 1) * 128 + d]),
                 f2b(Wmsg[(k4 + 2) * 128 + d]), f2b(Wmsg[(k4 + 3) * 128 + d])};
      *(u16x4*)&WhImg[(d << 7) + k4] = v;
    }
  } else if (b == 1) {
#pragma unroll
    for (int it = 0; it < 8; ++it) {
      int g = t + (it << 8);
      int d = g >> 4, k4 = (g & 15) << 2;
      u16x4 v = {f2b(Wmsg[(128 + k4 + 0) * 128 + d]), f2b(Wmsg[(128 + k4 + 1) * 128 + d]),
                 f2b(Wmsg[(128 + k4 + 2) * 128 + d]), f2b(Wmsg[(128 + k4 + 3) * 128 + d])};
      *(u16x4*)&WcImg[(d << 6) + k4] = v;
    }
  } else {
#pragma unroll
    for (int it = 0; it < 16; ++it) {
      int g = t + (it << 8);
      int d = g >> 5, k4 = (g & 31) << 2;
      u16x4 v = {f2b(Wlin[(k4 + 0) * 128 + d]), f2b(Wlin[(k4 + 1) * 128 + d]),
                 f2b(Wlin[(k4 + 2) * 128 + d]), f2b(Wlin[(k4 + 3) * 128 + d])};
      *(u16x4*)&WlImg[(d << 7) + k4] = v;
    }
  }
}

// ---- hierarchical scan ----
__global__ __launch_bounds__(256) void k_scan1(const uint32_t* __restrict__ deg,
                                               uint32_t* __restrict__ ex,
                                               uint32_t* __restrict__ bsum) {
  __shared__ uint32_t s[256];
  int t = threadIdx.x;
  int i = blockIdx.x * 256 + t;
  uint32_t v = (i < NN) ? deg[i] : 0u;
  s[t] = v;
  __syncthreads();
#pragma unroll
  for (int off = 1; off < 256; off <<= 1) {
    uint32_t y = (t >= off) ? s[t - off] : 0u;
    __syncthreads();
    s[t] += y;
    __syncthreads();
  }
  if (i < NN) ex[i] = s[t] - v;
  if (t == 255) bsum[blockIdx.x] = s[255];
}

__global__ __launch_bounds__(256) void k_scan2(const uint32_t* __restrict__ bsum,
                                               uint32_t* __restrict__ boff) {
  __shared__ uint32_t s[256];
  int t = threadIdx.x;
  uint32_t v = (t < NBLK_N) ? bsum[t] : 0u;
  s[t] = v;
  __syncthreads();
#pragma unroll
  for (int off = 1; off < 256; off <<= 1) {
    uint32_t y = (t >= off) ? s[t - off] : 0u;
    __syncthreads();
    s[t] += y;
    __syncthreads();
  }
  boff[t] = s[t] - v;
}

__global__ __launch_bounds__(256) void k_scan3(const uint32_t* __restrict__ ex,
                                               const uint32_t* __restrict__ boff,
                                               uint32_t* __restrict__ cursor) {
  int i = blockIdx.x * 256 + threadIdx.x;
  if (i < NN) cursor[i] = ex[i] + boff[blockIdx.x];
}

// k_perm SORTED: 8 threads/edge; scatter bf16 [attr|tim] row to sorted slot.
// sd[pos] = src | (dst<<16)  (both < 65536)
__global__ __launch_bounds__(256) void k_perm_s(const int* __restrict__ ei,
                                                const float* __restrict__ attr,
                                                const float* __restrict__ tim,
                                                uint32_t* __restrict__ cursor,
                                                u16* __restrict__ Asorted,
                                                uint32_t* __restrict__ sd) {
  const int t = threadIdx.x;
  const int j = t & 7;
  const long e = (long)blockIdx.x * 32 + (t >> 3);
  const bool v = e < NE;
  uint32_t pos = 0, sdv = 0;
  if (v && j == 0) {
    uint32_t src = (uint32_t)ei[e];
    uint32_t dst = (uint32_t)ei[NE + e];
    sdv = src | (dst << 16);
    pos = atomicAdd(&cursor[dst], 1u);
  }
  pos = __shfl(pos, 0, 8);
  if (v) {
    f32x4 va = *(const f32x4*)(attr + ((size_t)e << 5) + (j << 2));
    f32x4 vt = *(const f32x4*)(tim + ((size_t)e << 5) + (j << 2));
    u16x4 ba = {f2b(va[0]), f2b(va[1]), f2b(va[2]), f2b(va[3])};
    u16x4 bt = {f2b(vt[0]), f2b(vt[1]), f2b(vt[2]), f2b(vt[3])};
    *(u16x4*)&Asorted[((size_t)pos << 6) + (j << 2)] = ba;
    *(u16x4*)&Asorted[((size_t)pos << 6) + 32 + (j << 2)] = bt;
    if (j == 0) sd[pos] = sdv;
  }
}

// k_perm fallback: permutation index only
__global__ __launch_bounds__(256) void k_perm_f(const int* __restrict__ ei,
                                                uint32_t* __restrict__ cursor,
                                                int* __restrict__ perm,
                                                uint32_t* __restrict__ sd) {
  int i = blockIdx.x * 256 + threadIdx.x;
  if (i < NE) {
    uint32_t s = (uint32_t)ei[i], d = (uint32_t)ei[NE + i];
    uint32_t pos = atomicAdd(&cursor[d], 1u);
    perm[pos] = i;
    sd[pos] = s | (d << 16);
  }
}

// K1: Hp = bf16(hidden @ W_msg[0:128,:] + b_msg), 64-row tiles, B from global
// WhImg (L1-hot). LDS = A only (16 KB). Fused deg count.
__global__ __launch_bounds__(256) void k_hp(const float* __restrict__ hidden,
                                            const u16* __restrict__ WhImg,
                                            const float* __restrict__ bmsg,
                                            const int* __restrict__ ei,
                                            uint32_t* __restrict__ deg,
                                            u16* __restrict__ Hp) {
  __shared__ u16 sA[64 * 128];
  const int t = threadIdx.x;
  const int row0 = blockIdx.x << 6;
  for (int i = blockIdx.x * 256 + t; i < NE; i += DEG_STRIDE)
    atomicAdd(&deg[ei[NE + i]], 1u);
#pragma unroll
  for (int it = 0; it < 8; ++it) {
    int li = t + (it << 8);
    int row = li >> 5, c4 = li & 31;
    int n = row0 + row;
    f32x4 v = {0.f, 0.f, 0.f, 0.f};
    if (n < NN) v = *(const f32x4*)(hidden + ((size_t)n << 7) + (c4 << 2));
    u16x4 b = {f2b(v[0]), f2b(v[1]), f2b(v[2]), f2b(v[3])};
    *(u16x4*)&sA[(row << 7) + ((((c4 >> 1) ^ (row & 15)) << 3) + ((c4 & 1) << 2))] = b;
  }
  __syncthreads();
  const int lane = t & 63, w = t >> 6;
  const int quad = lane >> 4, lr = lane & 15;
  f32x4 c[4][2];
#pragma unroll
  for (int i = 0; i < 4; ++i)
#pragma unroll
    for (int j = 0; j < 2; ++j) { f32x4 z = {0.f, 0.f, 0.f, 0.f}; c[i][j] = z; }
#pragma unroll
  for (int ks = 0; ks < 128; ks += 32) {
    const int gi = (ks >> 3) + quad;
    bf16x8 a[4], b[2];
#pragma unroll
    for (int i = 0; i < 4; ++i) {
      int row = (i << 4) + lr;
      a[i] = *(const bf16x8*)&sA[(row << 7) + ((gi ^ (row & 15)) << 3)];
    }
#pragma unroll
    for (int j = 0; j < 2; ++j) {
      int col = (w << 5) + (j << 4) + lr;
      b[j] = *(const bf16x8*)&WhImg[(col << 7) + (gi << 3)];
    }
#pragma unroll
    for (int i = 0; i < 4; ++i)
#pragma unroll
      for (int j = 0; j < 2; ++j)
        c[i][j] = __builtin_amdgcn_mfma_f32_16x16x32_bf16(a[i], b[j], c[i][j], 0, 0, 0);
  }
#pragma unroll
  for (int j = 0; j < 2; ++j) {
    int d = (w << 5) + (j << 4) + lr;
    float bias = bmsg[d];
#pragma unroll
    for (int i = 0; i < 4; ++i) {
      int nb = row0 + (i << 4) + (quad << 2);
#pragma unroll
      for (int r = 0; r < 4; ++r) {
        int n = nb + r;
        if (n < NN) Hp[((size_t)n << 7) + d] = f2b(c[i][j][r] + bias);
      }
    }
  }
}

// K2: B from global WcImg; A from Asorted (SORTED) or LDS perm-gather (fallback).
template <bool SORTED>
__global__ __launch_bounds__(256, 4) void k_edge3(const float* __restrict__ attr,
                                                  const float* __restrict__ tim,
                                                  const int* __restrict__ perm,
                                                  const u16* __restrict__ Asorted,
                                                  const u16* __restrict__ WcImg,
                                                  const uint32_t* __restrict__ sd,
                                                  const u16* __restrict__ Hp,
                                                  float* __restrict__ acc) {
  __shared__ union { u16 A[64 * 64]; float C[64 * 128]; } lds;  // 32 KB
  __shared__ int sdst[64];
  const int t = threadIdx.x;
  const long e0 = (long)blockIdx.x << 6;

  if (!SORTED) {
#pragma unroll
    for (int it = 0; it < 2; ++it) {
      int li = t + (it << 8);
      int row = li >> 3, c4 = li & 7;
      long sg = e0 + row;
      f32x4 va = {0.f, 0.f, 0.f, 0.f}, vt = {0.f, 0.f, 0.f, 0.f};
      if (sg < NE) {
        int e = perm[sg];
        va = *(const f32x4*)(attr + ((size_t)e << 5) + (c4 << 2));
        vt = *(const f32x4*)(tim + ((size_t)e << 5) + (c4 << 2));
      }
      int g0 = c4 >> 1, h = (c4 & 1) << 2;
      u16x4 ba = {f2b(va[0]), f2b(va[1]), f2b(va[2]), f2b(va[3])};
      u16x4 bt = {f2b(vt[0]), f2b(vt[1]), f2b(vt[2]), f2b(vt[3])};
      *(u16x4*)&lds.A[(row << 6) + (((g0 ^ (row & 7)) << 3) + h)] = ba;
      *(u16x4*)&lds.A[(row << 6) + ((((g0 + 4) ^ (row & 7)) << 3) + h)] = bt;
    }
  }
  // per-slot src/dst + Hp register prefetch: 4 threads/slot
  const int s = t >> 2, q = t & 3;
  const long sg1 = e0 + s;
  const bool v1 = sg1 < NE;
  int src = 0, dstn = -1;
  if (v1) {
    uint32_t sdv = sd[sg1];
    src = (int)(sdv & 0xffffu);
    dstn = (int)(sdv >> 16);
  }
  u32x4 hp[4];
  if (v1) {
    const u32x4* hp4 = (const u32x4*)(Hp + ((size_t)src << 7) + (q << 5));
#pragma unroll
    for (int g = 0; g < 4; ++g) hp[g] = hp4[g];
  }
  if (q == 0) sdst[s] = v1 ? dstn : -1;
  __syncthreads();

  const int lane = t & 63, w = t >> 6;
  const int quad = lane >> 4, lr = lane & 15;
  f32x4 c[4][2];
#pragma unroll
  for (int i = 0; i < 4; ++i)
#pragma unroll
    for (int j = 0; j < 2; ++j) { f32x4 z = {0.f, 0.f, 0.f, 0.f}; c[i][j] = z; }
#pragma unroll
  for (int ks = 0; ks < 64; ks += 32) {
    const int gi = (ks >> 3) + quad;
    bf16x8 a[4], b[2];
#pragma unroll
    for (int i = 0; i < 4; ++i) {
      int row = (i << 4) + lr;
      if (SORTED)
        a[i] = *(const bf16x8*)&Asorted[((size_t)(e0 + row) << 6) + (gi << 3)];
      else
        a[i] = *(const bf16x8*)&lds.A[(row << 6) + ((gi ^ (row & 7)) << 3)];
    }
#pragma unroll
    for (int j = 0; j < 2; ++j) {
      int col = (w << 5) + (j << 4) + lr;
      b[j] = *(const bf16x8*)&WcImg[(col << 6) + (gi << 3)];
    }
#pragma unroll
    for (int i = 0; i < 4; ++i)
#pragma unroll
      for (int j = 0; j < 2; ++j)
        c[i][j] = __builtin_amdgcn_mfma_f32_16x16x32_bf16(a[i], b[j], c[i][j], 0, 0, 0);
  }
  __syncthreads();
#pragma unroll
  for (int i = 0; i < 4; ++i)
#pragma unroll
    for (int j = 0; j < 2; ++j)
#pragma unroll
      for (int r = 0; r < 4; ++r) {
        int row = (i << 4) + (quad << 2) + r;
        int col = (w << 5) + (j << 4) + lr;
        lds.C[(row << 7) + ((((col >> 2) ^ (row & 31)) << 2) + (col & 3))] = c[i][j][r];
      }
  __syncthreads();
  // stage 1: msg = relu(P + Hp[src]); thread (s,q) owns cols q*32..+31
  if (v1) {
#pragma unroll
    for (int g = 0; g < 8; ++g) {
      int cb = (q << 5) + (g << 2);
      float* p = &lds.C[(s << 7) + ((((cb >> 2) ^ (s & 31)) << 2))];
      f32x4 cv = *(const f32x4*)p;
      uint32_t w0 = hp[g >> 1][(g & 1) << 1];
      uint32_t w1 = hp[g >> 1][((g & 1) << 1) + 1];
      cv[0] = fmaxf(cv[0] + b2f(w0 & 0xffffu), 0.f);
      cv[1] = fmaxf(cv[1] + b2f(w0 >> 16), 0.f);
      cv[2] = fmaxf(cv[2] + b2f(w1 & 0xffffu), 0.f);
      cv[3] = fmaxf(cv[3] + b2f(w1 >> 16), 0.f);
      *(f32x4*)p = cv;
    }
  }
  __syncthreads();
  // stage 2: segmented reduction, 2 halves x 128 cols
  {
    const int col = t & 127, half = t >> 7;
    const int beg = half << 5, end = beg + 32;
    int cur = sdst[beg];
    float sum = 0.f;
    int runstart = beg;
    for (int ss = beg; ss < end; ++ss) {
      int d = sdst[ss];
      if (d != cur) {
        if (cur >= 0) {
          float* p = acc + ((size_t)cur << 7) + col;
          if (runstart == beg) unsafeAtomicAdd(p, sum);
          else *p = sum;
        }
        cur = d; sum = 0.f; runstart = ss;
      }
      sum += lds.C[(ss << 7) + ((((col >> 2) ^ (ss & 31)) << 2) + (col & 3))];
    }
    if (cur >= 0) unsafeAtomicAdd(acc + ((size_t)cur << 7) + col, sum);
  }
}

// K3 (in-place): out = dropout(relu(LN((acc+boundary) @ W_lin + b_lin)))
// 64-row tiles, B from global WlImg, LDS 32 KB union.
__global__ __launch_bounds__(256) void k_out(float* accout,
                                             const float* __restrict__ bnd,
                                             const u16* __restrict__ WlImg,
                                             const float* __restrict__ blin,
                                             const float* __restrict__ gam,
                                             const float* __restrict__ bet) {
  __shared__ union { u16 A[64 * 128]; float C[64 * 128]; } lds;  // 32 KB
  const int t = threadIdx.x;
  const int row0 = blockIdx.x << 6;
#pragma unroll
  for (int it = 0; it < 8; ++it) {
    int li = t + (it << 8);
    int row = li >> 5, c4 = li & 31;
    int n = row0 + row;
    f32x4 v = {0.f, 0.f, 0.f, 0.f};
    if (n < NN) {
      f32x4 a = *(const f32x4*)(accout + ((size_t)n << 7) + (c4 << 2));
      f32x4 b = *(const f32x4*)(bnd + ((size_t)n << 7) + (c4 << 2));
      v = a + b;
    }
    u16x4 bb = {f2b(v[0]), f2b(v[1]), f2b(v[2]), f2b(v[3])};
    *(u16x4*)&lds.A[(row << 7) + ((((c4 >> 1) ^ (row & 15)) << 3) + ((c4 & 1) << 2))] = bb;
  }
  __syncthreads();
  const int lane = t & 63, w = t >> 6;
  const int quad = lane >> 4, lr = lane & 15;
  f32x4 c[4][2];
#pragma unroll
  for (int i = 0; i < 4; ++i)
#pragma unroll
    for (int j = 0; j < 2; ++j) { f32x4 z = {0.f, 0.f, 0.f, 0.f}; c[i][j] = z; }
#pragma unroll
  for (int ks = 0; ks < 128; ks += 32) {
    const int gi = (ks >> 3) + quad;
    bf16x8 a[4], b[2];
#pragma unroll
    for (int i = 0; i < 4; ++i) {
      int row = (i << 4) + lr;
      a[i] = *(const bf16x8*)&lds.A[(row << 7) + ((gi ^ (row & 15)) << 3)];
    }
#pragma unroll
    for (int j = 0; j < 2; ++j) {
      int col = (w << 5) + (j << 4) + lr;
      b[j] = *(const bf16x8*)&WlImg[(col << 7) + (gi << 3)];
    }
#pragma unroll
    for (int i = 0; i < 4; ++i)
#pragma unroll
      for (int j = 0; j < 2; ++j)
        c[i][j] = __builtin_amdgcn_mfma_f32_16x16x32_bf16(a[i], b[j], c[i][j], 0, 0, 0);
  }
  __syncthreads();  // all waves done reading A before C overwrites
#pragma unroll
  for (int i = 0; i < 4; ++i)
#pragma unroll
    for (int j = 0; j < 2; ++j)
#pragma unroll
      for (int r = 0; r < 4; ++r) {
        int row = (i << 4) + (quad << 2) + r;
        int col = (w << 5) + (j << 4) + lr;
        lds.C[(row << 7) + ((((col >> 2) ^ (row & 31)) << 2) + (col & 3))] = c[i][j][r];
      }
  __syncthreads();
  // LN + relu + dropout: 4 threads/row, thread q owns cols q*32..+31
  const int row = t >> 2, q = t & 3;
  const int n = row0 + row;
  float s1 = 0.f, s2 = 0.f;
  if (n < NN) {
#pragma unroll
    for (int g = 0; g < 8; ++g) {
      int g5 = (q << 3) + g;
      f32x4 cv = *(const f32x4*)&lds.C[(row << 7) + ((g5 ^ (row & 31)) << 2)];
      f32x4 bl = *(const f32x4*)(blin + (g5 << 2));
#pragma unroll
      for (int m = 0; m < 4; ++m) {
        float x = cv[m] + bl[m];
        s1 += x; s2 += x * x;
      }
    }
  }
  s1 += __shfl_xor(s1, 1, 64); s1 += __shfl_xor(s1, 2, 64);
  s2 += __shfl_xor(s2, 1, 64); s2 += __shfl_xor(s2, 2, 64);
  if (n < NN) {
    const float mean = s1 * 0.0078125f;
    const float var = s2 * 0.0078125f - mean * mean;
    const float inv = 1.0f / sqrtf(var + 1e-5f);
#pragma unroll
    for (int g = 0; g < 8; ++g) {
      int g5 = (q << 3) + g;
      int d0 = g5 << 2;
      f32x4 cv = *(const f32x4*)&lds.C[(row << 7) + ((g5 ^ (row & 31)) << 2)];
      f32x4 bl = *(const f32x4*)(blin + d0);
      f32x4 gm = *(const f32x4*)(gam + d0);
      f32x4 bb = *(const f32x4*)(bet + d0);
      f32x4 o;
#pragma unroll
      for (int m = 0; m < 4; ++m) {
        float x = cv[m] + bl[m];
        float y = fmaxf((x - mean) * inv * gm[m] + bb[m], 0.f);
        uint32_t jj = ((uint32_t)n << 7) + (uint32_t)(d0 + m);
        o[m] = jax_keep(jj) ? (y * (1.0f / 0.9f)) : 0.0f;
      }
      *(f32x4*)(accout + ((size_t)n << 7) + d0) = o;
    }
  }
}

extern "C" void kernel_launch(void* const* d_in, const int* in_sizes, int n_in,
                              void* d_out, int out_size, void* d_ws, size_t ws_size,
                              hipStream_t stream) {
  (void)in_sizes; (void)n_in; (void)out_size;
  const float* hidden = (const float*)d_in[0];
  const int*   ei     = (const int*)d_in[1];
  const float* attr   = (const float*)d_in[2];
  const float* tim    = (const float*)d_in[3];
  const float* bnd    = (const float*)d_in[4];
  const float* Wmsg   = (const float*)d_in[5];
  const float* bmsg   = (const float*)d_in[6];
  const float* Wlin   = (const float*)d_in[7];
  const float* blin   = (const float*)d_in[8];
  const float* gam    = (const float*)d_in[9];
  const float* bet    = (const float*)d_in[10];

  float* acc = (float*)d_out;  // [N,128] f32 accumulator, finalized in-place

  char* ws = (char*)d_ws;
  u16*      Hp     = (u16*)(ws + 0);              // 12,800,000
  u16*      WhImg  = (u16*)(ws + 12800000);       //     32,768
  u16*      WcImg  = (u16*)(ws + 12832768);       //     16,384
  u16*      WlImg  = (u16*)(ws + 12849152);       //     32,768
  uint32_t* deg    = (uint32_t*)(ws + 12881920);  //    200,000
  uint32_t* cursor = (uint32_t*)(ws + 13081920);  //    200,000
  uint32_t* bsum   = (uint32_t*)(ws + 13281920);  //      1,024
  uint32_t* boff   = (uint32_t*)(ws + 13282944);  //      1,024
  uint32_t* ex     = (uint32_t*)(ws + 13283968);  //    200,000
  uint32_t* sd     = (uint32_t*)(ws + 13483968);  //  2,000,128
  u16*      Asort  = (u16*)(ws + 15484096);       // 64,004,096 (sorted path)
  int*      perm   = (int*)(ws + 15484096);       //  2,000,000 (fallback)
  const bool sorted = ws_size >= (size_t)(15484096 + (size_t)NEPAD * 64 * 2);

  hipMemsetAsync(deg, 0, (size_t)NN * 4, stream);
  hipMemsetAsync(acc, 0, (size_t)NN * 128 * 4, stream);

  k_prep <<<dim3(3), dim3(256), 0, stream>>>(Wmsg, Wlin, WhImg, WcImg, WlImg);
  k_hp   <<<dim3(NT_BLOCKS), dim3(256), 0, stream>>>(hidden, WhImg, bmsg, ei, deg, Hp);
  k_scan1<<<dim3(NBLK_N), dim3(256), 0, stream>>>(deg, ex, bsum);
  k_scan2<<<dim3(1), dim3(256), 0, stream>>>(bsum, boff);
  k_scan3<<<dim3(NBLK_N), dim3(256), 0, stream>>>(ex, boff, cursor);
  if (sorted) {
    k_perm_s<<<dim3((NE + 31) / 32), dim3(256), 0, stream>>>(ei, attr, tim, cursor, Asort, sd);
    k_edge3<true><<<dim3(NEPAD / SPB), dim3(256), 0, stream>>>(attr, tim, nullptr, Asort, WcImg, sd, Hp, acc);
  } else {
    k_perm_f<<<dim3((NE + 255) / 256), dim3(256), 0, stream>>>(ei, cursor, perm, sd);
    k_edge3<false><<<dim3(NEPAD / SPB), dim3(256), 0, stream>>>(attr, tim, perm, nullptr, WcImg, sd, Hp, acc);
  }
  k_out  <<<dim3(NT_BLOCKS), dim3(256), 0, stream>>>(acc, bnd, WlImg, blin, gam, bet);
}